// Round 1
// 1157.856 us; speedup vs baseline: 1.0431x; 1.0431x over previous
//
#include <hip/hip_runtime.h>

// WindowAttention, fully fused: B=4096 windows, N=49 tokens, DIM=384, H=12, D=32.
// kernel 1 (prep): w_qkv^T, w_proj^T (bf16), bias-init frags (f32, C-frag layout, /SCALE).
// kernel 2 (fused_win): one block per window, 8 waves, dynamic LDS 158 KB:
//   phase0 stage x f32->bf16 chunked [48][49][16B] (+16B zero page)
//   phase1 QKV GEMM (3 passes, wave=48 cols), writes Q/K chunked + V^T chunked
//   phase2 per-head attention (poly-norm), P via per-wave scratch over dead x,
//          O bf16 over dead Q region
//   phase3 proj GEMM from O-LDS + bias -> out f32
// WS: wqt [1152][384] bf16 @0 ; wpt [384][384] bf16 @884736 ; bini [12][4][4][256] f32 @1179648

using s16x8 = __attribute__((ext_vector_type(8))) short;
using u16x4 = __attribute__((ext_vector_type(4))) unsigned short;
using f32x4 = __attribute__((ext_vector_type(4))) float;

__device__ __forceinline__ short f2bf(float f) {
  unsigned int u = __float_as_uint(f);
  u += 0x7fffu + ((u >> 16) & 1u);          // round-to-nearest-even
  return (short)(u >> 16);
}

// ---- LDS map (bytes) ----
#define LDS_X    0        // x chunks [48][49][16]; later per-wave P scratch (wave*3136, [4][49][16])
#define LDS_Q    37632    // Q chunks [48][49][16]; later O (same layout)
#define LDS_K    75264    // K chunks [48][49][16]
#define LDS_V    112896   // V^T chunks [12 h][8 mchunk][32 d][16]
#define LDS_ZERO 162048   // 16 B of zeros (row>=49 redirect target)
#define LDS_TOTAL 162064

// ---------------- kernel 1: weights^T + bias frags ----------------
__global__ __launch_bounds__(256) void prep(const float* __restrict__ wqkv,
                                            const float* __restrict__ wproj,
                                            const float* __restrict__ btab,
                                            const int* __restrict__ rel,
                                            short* __restrict__ wqt,
                                            short* __restrict__ wpt,
                                            float* __restrict__ bini) {
  int i = blockIdx.x * 256 + threadIdx.x;
  if (i < 442368) {                      // w_qkv^T [1152][384]
    int c = i / 384, kx = i - c * 384;
    wqt[i] = f2bf(wqkv[kx * 1152 + c]);
  } else if (i < 442368 + 147456) {      // w_proj^T [384][384]
    int j = i - 442368;
    int c = j / 384, kx = j - c * 384;
    wpt[j] = f2bf(wproj[kx * 384 + c]);
  } else if (i < 442368 + 147456 + 49152) {
    int j = i - (442368 + 147456);       // [head][fi][fj][lane*4+r]
    int head = j >> 12;
    int rem = j & 4095;
    int fi = rem >> 10; int rem2 = rem & 1023;
    int fj = rem2 >> 8; int rem3 = rem2 & 255;
    int l = rem3 >> 2;  int r = rem3 & 3;
    int row = fi * 16 + (l >> 4) * 4 + r;   // query index
    int col = fj * 16 + (l & 15);           // key index
    float val = 0.f;
    if (row < 49 && col < 49)
      val = btab[rel[row * 49 + col] * 12 + head] * 5.656854249492381f; // /SCALE
    bini[j] = val;
  }
}

// ---------------- kernel 2: fully fused per-window pipeline ----------------
__global__ __launch_bounds__(512, 2) void fused_win(const float* __restrict__ x,
                                                    const short* __restrict__ wqt,
                                                    const short* __restrict__ wpt,
                                                    const float* __restrict__ bias_proj,
                                                    const float* __restrict__ bini,
                                                    float* __restrict__ out) {
  extern __shared__ char smem[];
  const int t = threadIdx.x;
  const int wave = t >> 6, lane = t & 63, quad = lane >> 4, l15 = lane & 15;
  const size_t xbase = (size_t)blockIdx.x * (49 * 384);

  // ---- phase 0: stage x f32 -> bf16, chunked [48][49][16B] ----
  for (int task = t; task < 2352; task += 512) {        // 49 rows x 48 chunks
    int r = task / 48, c = task - r * 48;               // global read is task*32 B, contiguous
    const float4* src = (const float4*)(x + xbase + r * 384 + c * 8);
    float4 a = src[0], b = src[1];
    s16x8 o;
    o[0] = f2bf(a.x); o[1] = f2bf(a.y); o[2] = f2bf(a.z); o[3] = f2bf(a.w);
    o[4] = f2bf(b.x); o[5] = f2bf(b.y); o[6] = f2bf(b.z); o[7] = f2bf(b.w);
    *(s16x8*)(smem + (c * 49 + r) * 16) = o;
  }
  if (t < 8) ((short*)(smem + LDS_ZERO))[t] = 0;
  __syncthreads();

  // ---- phase 1: QKV GEMM, 3 passes (Q, K, V), wave covers 48 cols of each part ----
  const int colbase = wave * 48;
  for (int p = 0; p < 3; ++p) {
    f32x4 acc[4][3] = {};
    const short* bsrc = wqt + (size_t)(p * 384 + colbase) * 384;
    for (int kt = 0; kt < 12; ++kt) {
      s16x8 af[4], bfr[3];
      const int cb = (kt * 4 + quad) * 784;
#pragma unroll
      for (int i = 0; i < 4; ++i) {
        int row = i * 16 + l15;
        af[i] = *(const s16x8*)(smem + ((row < 49) ? (cb + row * 16) : LDS_ZERO));
      }
#pragma unroll
      for (int j = 0; j < 3; ++j)       // wave's 64 lanes cover 16 rows x full 64B lines
        bfr[j] = *(const s16x8*)(bsrc + (j * 16 + l15) * 384 + kt * 32 + quad * 8);
#pragma unroll
      for (int i = 0; i < 4; ++i)
#pragma unroll
        for (int j = 0; j < 3; ++j)
          acc[i][j] = __builtin_amdgcn_mfma_f32_16x16x32_bf16(af[i], bfr[j], acc[i][j], 0, 0, 0);
    }
    if (p < 2) {
      // Q / K: chunked [48][49][16], chunk = gcol>>3, elem = gcol&7
      char* reg = smem + ((p == 0) ? LDS_Q : LDS_K);
#pragma unroll
      for (int j = 0; j < 3; ++j) {
        int gcol = colbase + j * 16 + l15;
        char* base = reg + (gcol >> 3) * 784 + (gcol & 7) * 2;
#pragma unroll
        for (int i = 0; i < 4; ++i)
#pragma unroll
          for (int r = 0; r < 4; ++r) {
            int tok = i * 16 + quad * 4 + r;
            if (tok < 49) *(short*)(base + tok * 16) = f2bf(acc[i][j][r]);
          }
      }
    } else {
      // V^T: [12][8][32][16]; 4 consecutive m per frag -> one b64 write (rows>=49 are exact 0)
#pragma unroll
      for (int j = 0; j < 3; ++j) {
        int gcol = colbase + j * 16 + l15;
        int h = gcol >> 5, dd = gcol & 31;
#pragma unroll
        for (int i = 0; i < 4; ++i) {
          u16x4 pk;
          pk[0] = (unsigned short)f2bf(acc[i][j][0]);
          pk[1] = (unsigned short)f2bf(acc[i][j][1]);
          pk[2] = (unsigned short)f2bf(acc[i][j][2]);
          pk[3] = (unsigned short)f2bf(acc[i][j][3]);
          int chunk = h * 8 + i * 2 + (quad >> 1);
          *(u16x4*)(smem + LDS_V + (chunk * 32 + dd) * 16 + (quad & 1) * 8) = pk;
        }
      }
    }
  }
  __syncthreads();

  // ---- phase 2: attention (poly-norm), one head per wave per round ----
  const float SC = 0.17677669529663687f;
  char* pbase = smem + wave * 3136;       // per-wave P scratch [4][49][16] over dead x
  for (int h = wave; h < 12; h += 8) {
    // S acc init = bias/SCALE in C-frag layout (0 outside 49x49)
    const float* bi = bini + h * 4096 + lane * 4;
    f32x4 sacc[4][4];
#pragma unroll
    for (int i = 0; i < 4; ++i)
#pragma unroll
      for (int j = 0; j < 4; ++j)
        sacc[i][j] = *(const f32x4*)(bi + (i * 4 + j) * 256);

    const int qoff = LDS_Q + (h * 4 + quad) * 784;
    const int koff = LDS_K + (h * 4 + quad) * 784;
    s16x8 aq[4], bk[4];
#pragma unroll
    for (int i = 0; i < 4; ++i) {
      int row = i * 16 + l15;
      aq[i] = *(const s16x8*)(smem + ((row < 49) ? (qoff + row * 16) : LDS_ZERO));
      bk[i] = *(const s16x8*)(smem + ((row < 49) ? (koff + row * 16) : LDS_ZERO));
    }
#pragma unroll
    for (int i = 0; i < 4; ++i)
#pragma unroll
      for (int j = 0; j < 4; ++j)
        sacc[i][j] = __builtin_amdgcn_mfma_f32_16x16x32_bf16(aq[i], bk[j], sacc[i][j], 0, 0, 0);

    float rs[4][4];
#pragma unroll
    for (int i = 0; i < 4; ++i)
#pragma unroll
      for (int r = 0; r < 4; ++r) rs[i][r] = 0.f;

    f32x4 oa[4][2] = {};
#pragma unroll
    for (int half = 0; half < 2; ++half) {
      // p = (s*SC)^2 for m-half, write P to per-wave scratch (zeros beyond 49 come out naturally)
#pragma unroll
      for (int jj = 0; jj < 2; ++jj) {
        int j = half * 2 + jj;
#pragma unroll
        for (int i = 0; i < 4; ++i)
#pragma unroll
          for (int r = 0; r < 4; ++r) {
            int tok = i * 16 + quad * 4 + r;
            float s = sacc[i][j][r] * SC;
            float pp = s * s;
            rs[i][r] += pp;
            if (tok < 49)
              *(short*)(pbase + ((jj * 2 + (l15 >> 3)) * 49 + tok) * 16 + (l15 & 7) * 2) = f2bf(pp);
          }
      }
      // PV for this m-half
#pragma unroll
      for (int i = 0; i < 4; ++i) {
        int row = i * 16 + l15;
        s16x8 ap = *(const s16x8*)((row < 49) ? (pbase + (quad * 49 + row) * 16)
                                              : (smem + LDS_ZERO));
#pragma unroll
        for (int nn = 0; nn < 2; ++nn) {
          s16x8 bv = *(const s16x8*)(smem + LDS_V +
                       ((h * 8 + half * 4 + quad) * 32 + nn * 16 + l15) * 16);
          oa[i][nn] = __builtin_amdgcn_mfma_f32_16x16x32_bf16(ap, bv, oa[i][nn], 0, 0, 0);
        }
      }
    }
    // row sums -> inv, normalize, write O bf16 over dead Q region (own head only)
#pragma unroll
    for (int i = 0; i < 4; ++i)
#pragma unroll
      for (int r = 0; r < 4; ++r) {
        float v = rs[i][r];
        v += __shfl_xor(v, 1);
        v += __shfl_xor(v, 2);
        v += __shfl_xor(v, 4);
        v += __shfl_xor(v, 8);
        rs[i][r] = 1.0f / (v + 1e-6f);
      }
#pragma unroll
    for (int nn = 0; nn < 2; ++nn) {
      char* obase = smem + LDS_Q + (h * 4 + nn * 2 + (l15 >> 3)) * 784 + (l15 & 7) * 2;
#pragma unroll
      for (int i = 0; i < 4; ++i)
#pragma unroll
        for (int r = 0; r < 4; ++r) {
          int tok = i * 16 + quad * 4 + r;
          if (tok < 49) *(short*)(obase + tok * 16) = f2bf(oa[i][nn][r] * rs[i][r]);
        }
    }
  }
  __syncthreads();

  // ---- phase 3: proj GEMM from O-LDS + bias ----
  f32x4 pacc[4][3] = {};
  const short* bsrc = wpt + (size_t)colbase * 384;
  for (int kt = 0; kt < 12; ++kt) {
    s16x8 af[4], bfr[3];
    const int cb = LDS_Q + (kt * 4 + quad) * 784;
#pragma unroll
    for (int i = 0; i < 4; ++i) {
      int row = i * 16 + l15;
      af[i] = *(const s16x8*)(smem + ((row < 49) ? (cb + row * 16) : LDS_ZERO));
    }
#pragma unroll
    for (int j = 0; j < 3; ++j)
      bfr[j] = *(const s16x8*)(bsrc + (j * 16 + l15) * 384 + kt * 32 + quad * 8);
#pragma unroll
    for (int i = 0; i < 4; ++i)
#pragma unroll
      for (int j = 0; j < 3; ++j)
        pacc[i][j] = __builtin_amdgcn_mfma_f32_16x16x32_bf16(af[i], bfr[j], pacc[i][j], 0, 0, 0);
  }
  float bj[3];
#pragma unroll
  for (int j = 0; j < 3; ++j) bj[j] = bias_proj[colbase + j * 16 + l15];
#pragma unroll
  for (int i = 0; i < 4; ++i)
#pragma unroll
    for (int r = 0; r < 4; ++r) {
      int tok = i * 16 + quad * 4 + r;
      if (tok < 49) {
        float* orow = out + xbase + (size_t)tok * 384 + colbase + l15;
#pragma unroll
        for (int j = 0; j < 3; ++j)
          orow[j * 16] = pacc[i][j][r] + bj[j];
      }
    }
}

extern "C" void kernel_launch(void* const* d_in, const int* in_sizes, int n_in,
                              void* d_out, int out_size, void* d_ws, size_t ws_size,
                              hipStream_t stream) {
  const float* x      = (const float*)d_in[0];
  const float* w_qkv  = (const float*)d_in[1];
  const float* w_proj = (const float*)d_in[2];
  const float* b_proj = (const float*)d_in[3];
  const float* btab   = (const float*)d_in[4];
  const int*   rel    = (const int*)d_in[5];

  char* ws = (char*)d_ws;
  short* wqt  = (short*)(ws);
  short* wpt  = (short*)(ws + 884736);
  float* bini = (float*)(ws + 1179648);

  // one-time opt-in for >64KB dynamic LDS (not a stream op; graph-capture safe)
  static int once = [] {
    return (int)hipFuncSetAttribute((const void*)fused_win,
                                    hipFuncAttributeMaxDynamicSharedMemorySize,
                                    LDS_TOTAL);
  }();
  (void)once;

  prep<<<2496, 256, 0, stream>>>(w_qkv, w_proj, btab, rel, wqt, wpt, bini);
  fused_win<<<4096, 512, LDS_TOTAL, stream>>>(x, wqt, wpt, b_proj, bini, (float*)d_out);
}